// Round 8
// baseline (673.071 us; speedup 1.0000x reference)
//
#include <hip/hip_runtime.h>

#define N_NODES 50000
#define N_EDGES 200000
#define DE 32
#define N_FRAG 10000
#define N_GRAPH 2000
#define BN_SLOTS 32

typedef __attribute__((ext_vector_type(8))) short short8;
typedef __attribute__((ext_vector_type(4))) float f32x4;

__device__ __forceinline__ unsigned short f2bf(float f) {
    unsigned u = __float_as_uint(f);
    u += 0x7FFF + ((u >> 16) & 1);      // RNE (no NaN inputs here)
    return (unsigned short)(u >> 16);
}

// split x = hi + lo (hi=bf16(x), lo=bf16(x-hi)); x-hi exact in fp32
__device__ __forceinline__ void split2(float f, unsigned short& h, unsigned short& l) {
    h = f2bf(f);
    float fh = __uint_as_float((unsigned)h << 16);
    l = f2bf(f - fh);
}

// 8 fp32 -> hi/lo bf16x8 (register-only)
__device__ __forceinline__ void split8(float4 a0, float4 a1, short8& hv, short8& lv) {
    unsigned short h, lo_;
    split2(a0.x, h, lo_); hv[0] = (short)h; lv[0] = (short)lo_;
    split2(a0.y, h, lo_); hv[1] = (short)h; lv[1] = (short)lo_;
    split2(a0.z, h, lo_); hv[2] = (short)h; lv[2] = (short)lo_;
    split2(a0.w, h, lo_); hv[3] = (short)h; lv[3] = (short)lo_;
    split2(a1.x, h, lo_); hv[4] = (short)h; lv[4] = (short)lo_;
    split2(a1.y, h, lo_); hv[5] = (short)h; lv[5] = (short)lo_;
    split2(a1.z, h, lo_); hv[6] = (short)h; lv[6] = (short)lo_;
    split2(a1.w, h, lo_); hv[7] = (short)h; lv[7] = (short)lo_;
}

// ---------------------------------------------------------------------------
// CSR build: in-degree count, hierarchical scan, fill
__global__ __launch_bounds__(256)
void count_deg_kernel(const int* __restrict__ ei, int* __restrict__ deg) {
    int e = blockIdx.x * 256 + threadIdx.x;
    if (e < N_EDGES) atomicAdd(&deg[ei[N_EDGES + e]], 1);
}

__global__ __launch_bounds__(256)
void block_sum_kernel(const int* __restrict__ deg, int* __restrict__ bsum) {
    int i = blockIdx.x * 256 + threadIdx.x;
    int v = (i < N_NODES) ? deg[i] : 0;
#pragma unroll
    for (int o = 1; o < 64; o <<= 1) v += __shfl_xor(v, o);
    __shared__ int wsum[4];
    if ((threadIdx.x & 63) == 0) wsum[threadIdx.x >> 6] = v;
    __syncthreads();
    if (threadIdx.x == 0) bsum[blockIdx.x] = wsum[0] + wsum[1] + wsum[2] + wsum[3];
}

__global__ __launch_bounds__(256)
void top_scan_kernel(int* __restrict__ bsum, int nb) {
    __shared__ int s[256];
    int t = threadIdx.x;
    s[t] = (t < nb) ? bsum[t] : 0;
    __syncthreads();
    for (int o = 1; o < 256; o <<= 1) {
        int v = s[t];
        int a = (t >= o) ? s[t - o] : 0;
        __syncthreads();
        s[t] = v + a;
        __syncthreads();
    }
    if (t < nb) bsum[t] = (t > 0) ? s[t - 1] : 0;
}

__global__ __launch_bounds__(256)
void final_scan_kernel(const int* __restrict__ deg, const int* __restrict__ bsum,
                       int* __restrict__ ptr) {
    __shared__ int s[256];
    int i = blockIdx.x * 256 + threadIdx.x;
    int t = threadIdx.x;
    int v = (i < N_NODES) ? deg[i] : 0;
    s[t] = v;
    __syncthreads();
    for (int o = 1; o < 256; o <<= 1) {
        int x = s[t];
        int a = (t >= o) ? s[t - o] : 0;
        __syncthreads();
        s[t] = x + a;
        __syncthreads();
    }
    int incl = s[t];
    int base = bsum[blockIdx.x];
    if (i < N_NODES) ptr[i] = base + incl - v;
    if (i == N_NODES - 1) ptr[N_NODES] = base + incl;
}

__global__ __launch_bounds__(256)
void fill_csr_kernel(const int* __restrict__ ei, const int* __restrict__ row_ptr,
                     int* __restrict__ fill, int* __restrict__ csr_src,
                     int* __restrict__ csr_eid) {
    int e = blockIdx.x * 256 + threadIdx.x;
    if (e >= N_EDGES) return;
    int dst = ei[N_EDGES + e];
    int pos = row_ptr[dst] + atomicAdd(&fill[dst], 1);
    csr_src[pos] = ei[e];
    csr_eid[pos] = e;
}

__global__ __launch_bounds__(256)
void segptr_kernel(const int* __restrict__ batch, int nseg, int* __restrict__ ptr) {
    int s = blockIdx.x * 256 + threadIdx.x;
    if (s > nseg) return;
    int lo = 0, hi = N_NODES;
    while (lo < hi) {
        int mid = (lo + hi) >> 1;
        if (batch[mid] < s) lo = mid + 1; else hi = mid;
    }
    ptr[s] = lo;
}

// ---------------------------------------------------------------------------
// W [K][256] fp32 -> fragment-swizzled BShi/BSlo:
// BS[kt][cg][lane][j] = split(W[kt*32 + (lane>>4)*8 + j][cg*16 + (lane&15)])
__global__ __launch_bounds__(256)
void bs_kernel(const float* __restrict__ W, unsigned short* __restrict__ BShi,
               unsigned short* __restrict__ BSlo, int K) {
    int id = blockIdx.x * 256 + threadIdx.x;
    if (id >= K * 256) return;
    int j  = id & 7;
    int l  = (id >> 3) & 63;
    int cg = (id >> 9) & 15;
    int kt = id >> 13;
    int col = cg * 16 + (l & 15);
    int k   = kt * 32 + (l >> 4) * 8 + j;
    unsigned short h, lo;
    split2(W[(size_t)k * 256 + col], h, lo);
    BShi[id] = h;
    BSlo[id] = lo;
}

// ---------------------------------------------------------------------------
// agg_e[n] = sum over incoming edges of relu(edge_attr[e])  [N,32]
__global__ __launch_bounds__(256)
void edge_gather_kernel(const float* __restrict__ ea, const int* __restrict__ row_ptr,
                        const int* __restrict__ csr_eid, float* __restrict__ agg_e) {
    int t = threadIdx.x;
    int g = t >> 3;
    int j = t & 7;
    int n = blockIdx.x * 32 + g;
    if (n >= N_NODES) return;
    int col = j << 2;
    float4 acc = {0.f, 0.f, 0.f, 0.f};
    int beg = row_ptr[n], end = row_ptr[n + 1];
    for (int e = beg; e < end; ++e) {
        int eid = csr_eid[e];
        float4 v = *(const float4*)(ea + (size_t)eid * DE + col);
        acc.x += fmaxf(v.x, 0.f);
        acc.y += fmaxf(v.y, 0.f);
        acc.z += fmaxf(v.z, 0.f);
        acc.w += fmaxf(v.w, 0.f);
    }
    *(float4*)(agg_e + (size_t)n * DE + col) = acc;
}

// agg[n][0:din] = xin[n] + sum relu(xin[src]);  agg[n][din:fin] = agg_e[n]
// If BNIN: xin is pre-BN h, apply x = scale*h + shift at load (per-column).
template <bool BNIN>
__global__ __launch_bounds__(256)
void gather_agg_kernel(const float* __restrict__ x, const int* __restrict__ row_ptr,
                       const int* __restrict__ csr_src, const float* __restrict__ agg_e,
                       float* __restrict__ agg, const float* __restrict__ bnsc,
                       const float* __restrict__ bnsh, int din, int fin, int gsize_log2) {
    int t = threadIdx.x;
    int g = t >> gsize_log2;
    int j = t & ((1 << gsize_log2) - 1);
    int n = blockIdx.x * (256 >> gsize_log2) + g;
    if (n >= N_NODES) return;
    int col = j << 2;
    float4 sc, sh;
    if (BNIN) {
        sc = *(const float4*)(bnsc + col);
        sh = *(const float4*)(bnsh + col);
    }
    float4 acc = *(const float4*)(x + (size_t)n * din + col);  // self term
    if (BNIN) {
        acc.x = fmaf(acc.x, sc.x, sh.x);
        acc.y = fmaf(acc.y, sc.y, sh.y);
        acc.z = fmaf(acc.z, sc.z, sh.z);
        acc.w = fmaf(acc.w, sc.w, sh.w);
    }
    int beg = row_ptr[n], end = row_ptr[n + 1];
    for (int e = beg; e < end; ++e) {
        int src = csr_src[e];
        float4 v = *(const float4*)(x + (size_t)src * din + col);
        if (BNIN) {
            v.x = fmaf(v.x, sc.x, sh.x);
            v.y = fmaf(v.y, sc.y, sh.y);
            v.z = fmaf(v.z, sc.z, sh.z);
            v.w = fmaf(v.w, sc.w, sh.w);
        }
        acc.x += fmaxf(v.x, 0.f);
        acc.y += fmaxf(v.y, 0.f);
        acc.z += fmaxf(v.z, 0.f);
        acc.w += fmaxf(v.w, 0.f);
    }
    *(float4*)(agg + (size_t)n * fin + col) = acc;
    if (j < 8) {
        float4 v = *(const float4*)(agg_e + (size_t)n * DE + (j << 2));
        *(float4*)(agg + (size_t)n * fin + din + (j << 2)) = v;
    }
}

// ---------------------------------------------------------------------------
// Split-bf16 MFMA GEMM v5: 1 wave per block, 32 rows x 256 cols, NO LDS,
// NO barriers. A loaded directly from global (coalesced 128B/row slices),
// split in-register; B pre-swizzled fragments from L2.
template <bool BN>
__global__ __launch_bounds__(64, 2)
void gemm_mfma_kernel(const float* __restrict__ A, const unsigned short* __restrict__ BShi,
                      const unsigned short* __restrict__ BSlo,
                      const float* __restrict__ bias, float* __restrict__ C, int K,
                      float* __restrict__ bnslot) {
    const int l = threadIdx.x;
    const int lr = l & 15;     // MFMA row/col within 16x16 tile
    const int lq = l >> 4;     // quad (k-group / acc row group)
    const int row0 = blockIdx.x << 5;   // 32 rows per wave

    f32x4 acc[2][16];
#pragma unroll
    for (int mt = 0; mt < 2; ++mt)
#pragma unroll
        for (int cg = 0; cg < 16; ++cg) acc[mt][cg] = (f32x4){0.f, 0.f, 0.f, 0.f};

    const int nkt = K >> 5;
    for (int kt = 0; kt < nkt; ++kt) {
        // A fragments: lane l reads A[row0+mt*16+lr][kt*32+lq*8 .. +8] (32B)
        short8 afh[2], afl[2];
#pragma unroll
        for (int mt = 0; mt < 2; ++mt) {
            int gr = row0 + mt * 16 + lr;
            float4 a0 = {0.f, 0.f, 0.f, 0.f}, a1 = {0.f, 0.f, 0.f, 0.f};
            if (gr < N_NODES) {
                const float* ap = A + (size_t)gr * K + (kt << 5) + (lq << 3);
                a0 = *(const float4*)ap;
                a1 = *(const float4*)(ap + 4);
            }
            split8(a0, a1, afh[mt], afl[mt]);
        }
        // column-group loop: B frag from L2, 6 MFMAs per cg
        const size_t bbase = ((size_t)kt * 16) * 512 + (l << 3);
#pragma unroll
        for (int cg = 0; cg < 16; ++cg) {
            short8 bfh = *(const short8*)(BShi + bbase + cg * 512);
            short8 bfl = *(const short8*)(BSlo + bbase + cg * 512);
#pragma unroll
            for (int mt = 0; mt < 2; ++mt) {
                acc[mt][cg] = __builtin_amdgcn_mfma_f32_16x16x32_bf16(
                    afl[mt], bfh, acc[mt][cg], 0, 0, 0);
                acc[mt][cg] = __builtin_amdgcn_mfma_f32_16x16x32_bf16(
                    afh[mt], bfl, acc[mt][cg], 0, 0, 0);
                acc[mt][cg] = __builtin_amdgcn_mfma_f32_16x16x32_bf16(
                    afh[mt], bfh, acc[mt][cg], 0, 0, 0);
            }
        }
    }

    // epilogue: bias + relu + store; BN stats reduced per-cg (shfl over quads)
    float* slot = BN ? (bnslot + (size_t)(blockIdx.x & (BN_SLOTS - 1)) * 512) : nullptr;
#pragma unroll
    for (int cg = 0; cg < 16; ++cg) {
        float bv = bias[cg * 16 + lr];
        float s = 0.f, q = 0.f;
#pragma unroll
        for (int mt = 0; mt < 2; ++mt) {
#pragma unroll
            for (int i = 0; i < 4; ++i) {
                int row = row0 + mt * 16 + lq * 4 + i;   // C/D: row = quad*4 + reg
                if (row < N_NODES) {
                    float o = fmaxf(acc[mt][cg][i] + bv, 0.f);
                    C[(size_t)row * 256 + cg * 16 + lr] = o;
                    if (BN) { s += o; q += o * o; }
                }
            }
        }
        if (BN) {
            s += __shfl_xor(s, 16); s += __shfl_xor(s, 32);
            q += __shfl_xor(q, 16); q += __shfl_xor(q, 32);
            if (lq == 0) {
                atomicAdd(&slot[cg * 16 + lr], s);
                atomicAdd(&slot[256 + cg * 16 + lr], q);
            }
        }
    }
}

// reduce BN_SLOTS slots -> scale/shift
__global__ void bn_finalize_kernel(const float* __restrict__ slots,
                                   const float* __restrict__ g, const float* __restrict__ beta,
                                   float* __restrict__ scale, float* __restrict__ shift) {
    int c = threadIdx.x;
    float s = 0.f, q = 0.f;
    for (int k = 0; k < BN_SLOTS; ++k) {
        s += slots[(size_t)k * 512 + c];
        q += slots[(size_t)k * 512 + 256 + c];
    }
    float mu = s * (1.0f / N_NODES);
    float var = q * (1.0f / N_NODES) - mu * mu;
    float rstd = rsqrtf(var + 1e-5f);
    float sc = g[c] * rstd;
    scale[c] = sc;
    shift[c] = beta[c] - mu * sc;
}

// segmented sqrt-pool with BN applied at load; no atomics
__global__ __launch_bounds__(256)
void pool_seg_kernel(const float* __restrict__ h, const int* __restrict__ ptr,
                     const float* __restrict__ bnsc, const float* __restrict__ bnsh,
                     float* __restrict__ out, int nseg) {
    int t = threadIdx.x;
    int g = t >> 6;
    int j = t & 63;
    int s = blockIdx.x * 4 + g;
    if (s >= nseg) return;
    int beg = ptr[s], end = ptr[s + 1];
    int col = j << 2;
    float4 sc = *(const float4*)(bnsc + col);
    float4 sh = *(const float4*)(bnsh + col);
    float4 acc = {0.f, 0.f, 0.f, 0.f};
    for (int i = beg; i < end; ++i) {
        float4 v = *(const float4*)(h + (size_t)i * 256 + col);
        acc.x += fmaf(v.x, sc.x, sh.x);
        acc.y += fmaf(v.y, sc.y, sh.y);
        acc.z += fmaf(v.z, sc.z, sh.z);
        acc.w += fmaf(v.w, sc.w, sh.w);
    }
    float w = rsqrtf(fmaxf((float)(end - beg), 1.0f));
    float4 o = {acc.x * w, acc.y * w, acc.z * w, acc.w * w};
    *(float4*)(out + (size_t)s * 256 + col) = o;
}

// ---------------------------------------------------------------------------
extern "C" void kernel_launch(void* const* d_in, const int* in_sizes, int n_in,
                              void* d_out, int out_size, void* d_ws, size_t ws_size,
                              hipStream_t stream) {
    const float* x  = (const float*)d_in[0];
    const float* ea = (const float*)d_in[1];
    const int*   ei = (const int*)d_in[2];
    const int*   fb = (const int*)d_in[3];
    const int*   gb = (const int*)d_in[4];
    const float* W1[3]   = {(const float*)d_in[5],  (const float*)d_in[11], (const float*)d_in[17]};
    const float* B1[3]   = {(const float*)d_in[6],  (const float*)d_in[12], (const float*)d_in[18]};
    const float* W2[3]   = {(const float*)d_in[7],  (const float*)d_in[13], (const float*)d_in[19]};
    const float* B2[3]   = {(const float*)d_in[8],  (const float*)d_in[14], (const float*)d_in[20]};
    const float* G[3]    = {(const float*)d_in[9],  (const float*)d_in[15], (const float*)d_in[21]};
    const float* BETA[3] = {(const float*)d_in[10], (const float*)d_in[16], (const float*)d_in[22]};

    const int FIN[3] = {160, 288, 288};
    const int NBLK = (N_NODES + 255) / 256;      // scan blocks

    float* ws = (float*)d_ws;
    size_t off = 0;
    float* agg   = ws + off; off += (size_t)N_NODES * 288;
    float* h1    = ws + off; off += (size_t)N_NODES * 256;
    float* xbuf  = ws + off; off += (size_t)N_NODES * 256;
    float* agg_e = ws + off; off += (size_t)N_NODES * DE;
    float* bnss  = ws + off; off += 3 * 512;                 // per layer: scale(256)|shift(256)
    float* bnslots = ws + off; off += (size_t)3 * BN_SLOTS * 512;
    unsigned short* w1hi[3]; unsigned short* w1lo[3];
    unsigned short* w2hi[3]; unsigned short* w2lo[3];
    {
        unsigned short* sw = (unsigned short*)(ws + off);
        unsigned short* sw0 = sw;
        for (int l = 0; l < 3; ++l) {
            w1hi[l] = sw; sw += 256 * FIN[l];
            w1lo[l] = sw; sw += 256 * FIN[l];
        }
        for (int l = 0; l < 3; ++l) {
            w2hi[l] = sw; sw += 256 * 256;
            w2lo[l] = sw; sw += 256 * 256;
        }
        off += (size_t)(sw - sw0 + 1) / 2;
    }
    int* iw      = (int*)(ws + off);
    int* row_ptr = iw;                     iw += N_NODES + 1;
    int* deg     = iw;                     iw += N_NODES;
    int* fill    = iw;                     iw += N_NODES;
    int* csr_src = iw;                     iw += N_EDGES;
    int* csr_eid = iw;                     iw += N_EDGES;
    int* frag_ptr = iw;                    iw += N_FRAG + 1;
    int* graph_ptr = iw;                   iw += N_GRAPH + 1;
    int* bsum    = iw;                     iw += NBLK;

    hipMemsetAsync(deg, 0, 2 * N_NODES * sizeof(int), stream);
    hipMemsetAsync(bnslots, 0, (size_t)3 * BN_SLOTS * 512 * sizeof(float), stream);

    // weight fragment-swizzle + bf16 hi/lo split (once per layer)
    for (int l = 0; l < 3; ++l) {
        bs_kernel<<<(FIN[l] * 256 + 255) / 256, 256, 0, stream>>>(W1[l], w1hi[l], w1lo[l], FIN[l]);
        bs_kernel<<<(256 * 256 + 255) / 256, 256, 0, stream>>>(W2[l], w2hi[l], w2lo[l], 256);
    }

    // CSR build (hierarchical scan)
    count_deg_kernel<<<(N_EDGES + 255) / 256, 256, 0, stream>>>(ei, deg);
    block_sum_kernel<<<NBLK, 256, 0, stream>>>(deg, bsum);
    top_scan_kernel<<<1, 256, 0, stream>>>(bsum, NBLK);
    final_scan_kernel<<<NBLK, 256, 0, stream>>>(deg, bsum, row_ptr);
    fill_csr_kernel<<<(N_EDGES + 255) / 256, 256, 0, stream>>>(ei, row_ptr, fill, csr_src, csr_eid);

    segptr_kernel<<<(N_FRAG + 1 + 255) / 256, 256, 0, stream>>>(fb, N_FRAG, frag_ptr);
    segptr_kernel<<<(N_GRAPH + 1 + 255) / 256, 256, 0, stream>>>(gb, N_GRAPH, graph_ptr);

    edge_gather_kernel<<<(N_NODES + 31) / 32, 256, 0, stream>>>(ea, row_ptr, csr_eid, agg_e);

    const int nblk_gemm = (N_NODES + 31) / 32;   // 1 wave (64 thr) per block
    const float* xin = x;
    for (int l = 0; l < 3; ++l) {
        const int din = (l == 0) ? 128 : 256;
        const int fin = FIN[l];
        const int gl2 = (din == 128) ? 5 : 6;
        const int npb = 256 >> gl2;
        float* slotsL = bnslots + (size_t)l * BN_SLOTS * 512;
        float* bscale = bnss + l * 512;
        float* bshift = bscale + 256;
        const float* psc = (l > 0) ? bnss + (l - 1) * 512 : nullptr;  // prev layer BN
        const float* psh = (l > 0) ? psc + 256 : nullptr;

        if (l == 0)
            gather_agg_kernel<false><<<(N_NODES + npb - 1) / npb, 256, 0, stream>>>(
                xin, row_ptr, csr_src, agg_e, agg, nullptr, nullptr, din, fin, gl2);
        else
            gather_agg_kernel<true><<<(N_NODES + npb - 1) / npb, 256, 0, stream>>>(
                xin, row_ptr, csr_src, agg_e, agg, psc, psh, din, fin, gl2);
        gemm_mfma_kernel<false><<<nblk_gemm, 64, 0, stream>>>(
            agg, w1hi[l], w1lo[l], B1[l], h1, fin, nullptr);
        gemm_mfma_kernel<true><<<nblk_gemm, 64, 0, stream>>>(
            h1, w2hi[l], w2lo[l], B2[l], xbuf, 256, slotsL);
        bn_finalize_kernel<<<1, 256, 0, stream>>>(slotsL, G[l], BETA[l], bscale, bshift);
        xin = xbuf;   // pre-BN h; BN applied by next consumer
    }

    const float* fsc = bnss + 2 * 512;   // layer-2 BN scale/shift
    const float* fsh = fsc + 256;
    pool_seg_kernel<<<(N_FRAG + 3) / 4, 256, 0, stream>>>(xbuf, frag_ptr, fsc, fsh,
                                                          (float*)d_out, N_FRAG);
    pool_seg_kernel<<<(N_GRAPH + 3) / 4, 256, 0, stream>>>(xbuf, graph_ptr, fsc, fsh,
                                                           (float*)d_out + (size_t)N_FRAG * 256, N_GRAPH);
}

// Round 9
// 508.531 us; speedup vs baseline: 1.3236x; 1.3236x over previous
//
#include <hip/hip_runtime.h>

#define N_NODES 50000
#define N_EDGES 200000
#define DE 32
#define N_FRAG 10000
#define N_GRAPH 2000
#define BN_SLOTS 32

typedef __attribute__((ext_vector_type(8))) short short8;
typedef __attribute__((ext_vector_type(4))) short s16x4;
typedef __attribute__((ext_vector_type(4))) float f32x4;
typedef __attribute__((ext_vector_type(4))) unsigned int u32x4;

__device__ __forceinline__ unsigned short f2bf(float f) {
    unsigned u = __float_as_uint(f);
    u += 0x7FFF + ((u >> 16) & 1);      // RNE (no NaN inputs here)
    return (unsigned short)(u >> 16);
}

// split x = hi + lo (hi=bf16(x), lo=bf16(x-hi)); x-hi exact in fp32
__device__ __forceinline__ void split2(float f, unsigned short& h, unsigned short& l) {
    h = f2bf(f);
    float fh = __uint_as_float((unsigned)h << 16);
    l = f2bf(f - fh);
}

// ---------------------------------------------------------------------------
// CSR build: in-degree count, hierarchical scan, fill
__global__ __launch_bounds__(256)
void count_deg_kernel(const int* __restrict__ ei, int* __restrict__ deg) {
    int e = blockIdx.x * 256 + threadIdx.x;
    if (e < N_EDGES) atomicAdd(&deg[ei[N_EDGES + e]], 1);
}

__global__ __launch_bounds__(256)
void block_sum_kernel(const int* __restrict__ deg, int* __restrict__ bsum) {
    int i = blockIdx.x * 256 + threadIdx.x;
    int v = (i < N_NODES) ? deg[i] : 0;
#pragma unroll
    for (int o = 1; o < 64; o <<= 1) v += __shfl_xor(v, o);
    __shared__ int wsum[4];
    if ((threadIdx.x & 63) == 0) wsum[threadIdx.x >> 6] = v;
    __syncthreads();
    if (threadIdx.x == 0) bsum[blockIdx.x] = wsum[0] + wsum[1] + wsum[2] + wsum[3];
}

__global__ __launch_bounds__(256)
void top_scan_kernel(int* __restrict__ bsum, int nb) {
    __shared__ int s[256];
    int t = threadIdx.x;
    s[t] = (t < nb) ? bsum[t] : 0;
    __syncthreads();
    for (int o = 1; o < 256; o <<= 1) {
        int v = s[t];
        int a = (t >= o) ? s[t - o] : 0;
        __syncthreads();
        s[t] = v + a;
        __syncthreads();
    }
    if (t < nb) bsum[t] = (t > 0) ? s[t - 1] : 0;
}

__global__ __launch_bounds__(256)
void final_scan_kernel(const int* __restrict__ deg, const int* __restrict__ bsum,
                       int* __restrict__ ptr) {
    __shared__ int s[256];
    int i = blockIdx.x * 256 + threadIdx.x;
    int t = threadIdx.x;
    int v = (i < N_NODES) ? deg[i] : 0;
    s[t] = v;
    __syncthreads();
    for (int o = 1; o < 256; o <<= 1) {
        int x = s[t];
        int a = (t >= o) ? s[t - o] : 0;
        __syncthreads();
        s[t] = x + a;
        __syncthreads();
    }
    int incl = s[t];
    int base = bsum[blockIdx.x];
    if (i < N_NODES) ptr[i] = base + incl - v;
    if (i == N_NODES - 1) ptr[N_NODES] = base + incl;
}

__global__ __launch_bounds__(256)
void fill_csr_kernel(const int* __restrict__ ei, const int* __restrict__ row_ptr,
                     int* __restrict__ fill, int* __restrict__ csr_src,
                     int* __restrict__ csr_eid) {
    int e = blockIdx.x * 256 + threadIdx.x;
    if (e >= N_EDGES) return;
    int dst = ei[N_EDGES + e];
    int pos = row_ptr[dst] + atomicAdd(&fill[dst], 1);
    csr_src[pos] = ei[e];
    csr_eid[pos] = e;
}

__global__ __launch_bounds__(256)
void segptr_kernel(const int* __restrict__ batch, int nseg, int* __restrict__ ptr) {
    int s = blockIdx.x * 256 + threadIdx.x;
    if (s > nseg) return;
    int lo = 0, hi = N_NODES;
    while (lo < hi) {
        int mid = (lo + hi) >> 1;
        if (batch[mid] < s) lo = mid + 1; else hi = mid;
    }
    ptr[s] = lo;
}

// ---------------------------------------------------------------------------
// W [K][256] fp32 -> fragment-swizzled BShi/BSlo:
// BS[kt][cg][lane][j] = split(W[kt*32 + (lane>>4)*8 + j][cg*16 + (lane&15)])
__global__ __launch_bounds__(256)
void bs_kernel(const float* __restrict__ W, unsigned short* __restrict__ BShi,
               unsigned short* __restrict__ BSlo, int K) {
    int id = blockIdx.x * 256 + threadIdx.x;
    if (id >= K * 256) return;
    int j  = id & 7;
    int l  = (id >> 3) & 63;
    int cg = (id >> 9) & 15;
    int kt = id >> 13;
    int col = cg * 16 + (l & 15);
    int k   = kt * 32 + (l >> 4) * 8 + j;
    unsigned short h, lo;
    split2(W[(size_t)k * 256 + col], h, lo);
    BShi[id] = h;
    BSlo[id] = lo;
}

// ---------------------------------------------------------------------------
// agg_e[n] = sum over incoming edges of relu(edge_attr[e])  [N,32]
__global__ __launch_bounds__(256)
void edge_gather_kernel(const float* __restrict__ ea, const int* __restrict__ row_ptr,
                        const int* __restrict__ csr_eid, float* __restrict__ agg_e) {
    int t = threadIdx.x;
    int g = t >> 3;
    int j = t & 7;
    int n = blockIdx.x * 32 + g;
    if (n >= N_NODES) return;
    int col = j << 2;
    float4 acc = {0.f, 0.f, 0.f, 0.f};
    int beg = row_ptr[n], end = row_ptr[n + 1];
    for (int e = beg; e < end; ++e) {
        int eid = csr_eid[e];
        float4 v = *(const float4*)(ea + (size_t)eid * DE + col);
        acc.x += fmaxf(v.x, 0.f);
        acc.y += fmaxf(v.y, 0.f);
        acc.z += fmaxf(v.z, 0.f);
        acc.w += fmaxf(v.w, 0.f);
    }
    *(float4*)(agg_e + (size_t)n * DE + col) = acc;
}

// agg[n][0:din] = xin[n] + sum relu(xin[src]);  agg[n][din:fin] = agg_e[n]
// If BNIN: xin is pre-BN h, apply x = scale*h + shift at load (per-column).
template <bool BNIN>
__global__ __launch_bounds__(256)
void gather_agg_kernel(const float* __restrict__ x, const int* __restrict__ row_ptr,
                       const int* __restrict__ csr_src, const float* __restrict__ agg_e,
                       float* __restrict__ agg, const float* __restrict__ bnsc,
                       const float* __restrict__ bnsh, int din, int fin, int gsize_log2) {
    int t = threadIdx.x;
    int g = t >> gsize_log2;
    int j = t & ((1 << gsize_log2) - 1);
    int n = blockIdx.x * (256 >> gsize_log2) + g;
    if (n >= N_NODES) return;
    int col = j << 2;
    float4 sc, sh;
    if (BNIN) {
        sc = *(const float4*)(bnsc + col);
        sh = *(const float4*)(bnsh + col);
    }
    float4 acc = *(const float4*)(x + (size_t)n * din + col);  // self term
    if (BNIN) {
        acc.x = fmaf(acc.x, sc.x, sh.x);
        acc.y = fmaf(acc.y, sc.y, sh.y);
        acc.z = fmaf(acc.z, sc.z, sh.z);
        acc.w = fmaf(acc.w, sc.w, sh.w);
    }
    int beg = row_ptr[n], end = row_ptr[n + 1];
    for (int e = beg; e < end; ++e) {
        int src = csr_src[e];
        float4 v = *(const float4*)(x + (size_t)src * din + col);
        if (BNIN) {
            v.x = fmaf(v.x, sc.x, sh.x);
            v.y = fmaf(v.y, sc.y, sh.y);
            v.z = fmaf(v.z, sc.z, sh.z);
            v.w = fmaf(v.w, sc.w, sh.w);
        }
        acc.x += fmaxf(v.x, 0.f);
        acc.y += fmaxf(v.y, 0.f);
        acc.z += fmaxf(v.z, 0.f);
        acc.w += fmaxf(v.w, 0.f);
    }
    *(float4*)(agg + (size_t)n * fin + col) = acc;
    if (j < 8) {
        float4 v = *(const float4*)(agg_e + (size_t)n * DE + (j << 2));
        *(float4*)(agg + (size_t)n * fin + din + (j << 2)) = v;
    }
}

// ---------------------------------------------------------------------------
// Fused per-layer MLP: xout = relu( relu(A@W1+b1) @ W2 + b2 ), + BN stats.
// h1 (32x256 tile) lives only in LDS (bf16 hi|lo packed u32, XOR-swizzled).
// Block: 256 thr (4 waves), 32 rows; wave w owns cols [w*64, w*64+64).
// Phase 2's K-loop has no barriers and no global A traffic.
#define H1_STRIDE 260   // dwords per row (16B aligned: 260*4=1040=65*16)
__global__ __launch_bounds__(256, 4)
void fused_mlp_kernel(const float* __restrict__ A,
                      const unsigned short* __restrict__ B1hi, const unsigned short* __restrict__ B1lo,
                      const float* __restrict__ bias1,
                      const unsigned short* __restrict__ B2hi, const unsigned short* __restrict__ B2lo,
                      const float* __restrict__ bias2,
                      float* __restrict__ C, int K1, float* __restrict__ bnslot) {
    __shared__ unsigned int sH[32 * H1_STRIDE];               // 33280 B
    __shared__ __align__(16) unsigned short sAhi[32 * 40];    // 2560 B
    __shared__ __align__(16) unsigned short sAlo[32 * 40];
    const int t = threadIdx.x;
    const int l = t & 63;
    const int w = t >> 6;
    const int lr = l & 15;
    const int lq = l >> 4;
    const int row0 = blockIdx.x << 5;       // 32 rows/block
    const int cb = w << 6;

    f32x4 acc[2][4];
#pragma unroll
    for (int mt = 0; mt < 2; ++mt)
#pragma unroll
        for (int nt = 0; nt < 4; ++nt) acc[mt][nt] = (f32x4){0.f, 0.f, 0.f, 0.f};

    // ---- phase 1: agg @ W1 ----
    const int r = t >> 3, q = t & 7;        // staging: row 0..31, 16B chunk 0..7
    const int gr = row0 + r;
    const bool ok = (gr < N_NODES);
    const float* ap = A + (size_t)gr * K1 + (q << 2);
    const int sOff = r * 40 + (q << 2);
    const int nkt1 = K1 >> 5;
    for (int kt = 0; kt < nkt1; ++kt) {
        float4 a = {0.f, 0.f, 0.f, 0.f};
        if (ok) a = *(const float4*)(ap + (kt << 5));
        s16x4 hv, lv;
        unsigned short h, lo_;
        split2(a.x, h, lo_); hv[0] = (short)h; lv[0] = (short)lo_;
        split2(a.y, h, lo_); hv[1] = (short)h; lv[1] = (short)lo_;
        split2(a.z, h, lo_); hv[2] = (short)h; lv[2] = (short)lo_;
        split2(a.w, h, lo_); hv[3] = (short)h; lv[3] = (short)lo_;
        *(s16x4*)&sAhi[sOff] = hv;
        *(s16x4*)&sAlo[sOff] = lv;
        __syncthreads();
        short8 afh[2], afl[2], bfh[4], bfl[4];
#pragma unroll
        for (int mt = 0; mt < 2; ++mt) {
            int so = (mt * 16 + lr) * 40 + (lq << 3);
            afh[mt] = *(const short8*)&sAhi[so];
            afl[mt] = *(const short8*)&sAlo[so];
        }
        const size_t bb = ((size_t)(kt * 16 + (w << 2))) * 512 + (l << 3);
#pragma unroll
        for (int nt = 0; nt < 4; ++nt) {
            bfh[nt] = *(const short8*)(B1hi + bb + nt * 512);
            bfl[nt] = *(const short8*)(B1lo + bb + nt * 512);
        }
#pragma unroll
        for (int mt = 0; mt < 2; ++mt)
#pragma unroll
            for (int nt = 0; nt < 4; ++nt) {
                acc[mt][nt] = __builtin_amdgcn_mfma_f32_16x16x32_bf16(afl[mt], bfh[nt], acc[mt][nt], 0, 0, 0);
                acc[mt][nt] = __builtin_amdgcn_mfma_f32_16x16x32_bf16(afh[mt], bfl[nt], acc[mt][nt], 0, 0, 0);
                acc[mt][nt] = __builtin_amdgcn_mfma_f32_16x16x32_bf16(afh[mt], bfh[nt], acc[mt][nt], 0, 0, 0);
            }
        __syncthreads();
    }

    // ---- epilogue 1: relu(h1) -> LDS (packed hi|lo, swizzled) ----
#pragma unroll
    for (int nt = 0; nt < 4; ++nt) {
        float bv = bias1[cb + nt * 16 + lr];
        int col = cb + nt * 16 + lr;
#pragma unroll
        for (int mt = 0; mt < 2; ++mt)
#pragma unroll
            for (int i = 0; i < 4; ++i) {
                int rr = mt * 16 + lq * 4 + i;       // local row 0..31
                float o = fmaxf(acc[mt][nt][i] + bv, 0.f);
                unsigned short h, lo_;
                split2(o, h, lo_);
                sH[rr * H1_STRIDE + (((col >> 2) ^ (rr & 7)) << 2) + (col & 3)] =
                    (unsigned)h | ((unsigned)lo_ << 16);
            }
    }
    __syncthreads();

    // ---- phase 2: h1 @ W2 (LDS A, no barriers) ----
#pragma unroll
    for (int mt = 0; mt < 2; ++mt)
#pragma unroll
        for (int nt = 0; nt < 4; ++nt) acc[mt][nt] = (f32x4){0.f, 0.f, 0.f, 0.f};
    for (int kt = 0; kt < 8; ++kt) {
        short8 afh[2], afl[2];
#pragma unroll
        for (int mt = 0; mt < 2; ++mt) {
            int rr = mt * 16 + lr;
            int s = rr & 7;
            int g0 = kt * 8 + lq * 2;
            u32x4 p0 = *(const u32x4*)&sH[rr * H1_STRIDE + ((g0 ^ s) << 2)];
            u32x4 p1 = *(const u32x4*)&sH[rr * H1_STRIDE + (((g0 + 1) ^ s) << 2)];
            short8 hv, lv;
            hv[0] = (short)(p0.x & 0xffff); lv[0] = (short)(p0.x >> 16);
            hv[1] = (short)(p0.y & 0xffff); lv[1] = (short)(p0.y >> 16);
            hv[2] = (short)(p0.z & 0xffff); lv[2] = (short)(p0.z >> 16);
            hv[3] = (short)(p0.w & 0xffff); lv[3] = (short)(p0.w >> 16);
            hv[4] = (short)(p1.x & 0xffff); lv[4] = (short)(p1.x >> 16);
            hv[5] = (short)(p1.y & 0xffff); lv[5] = (short)(p1.y >> 16);
            hv[6] = (short)(p1.z & 0xffff); lv[6] = (short)(p1.z >> 16);
            hv[7] = (short)(p1.w & 0xffff); lv[7] = (short)(p1.w >> 16);
            afh[mt] = hv; afl[mt] = lv;
        }
        short8 bfh[4], bfl[4];
        const size_t bb = ((size_t)(kt * 16 + (w << 2))) * 512 + (l << 3);
#pragma unroll
        for (int nt = 0; nt < 4; ++nt) {
            bfh[nt] = *(const short8*)(B2hi + bb + nt * 512);
            bfl[nt] = *(const short8*)(B2lo + bb + nt * 512);
        }
#pragma unroll
        for (int mt = 0; mt < 2; ++mt)
#pragma unroll
            for (int nt = 0; nt < 4; ++nt) {
                acc[mt][nt] = __builtin_amdgcn_mfma_f32_16x16x32_bf16(afl[mt], bfh[nt], acc[mt][nt], 0, 0, 0);
                acc[mt][nt] = __builtin_amdgcn_mfma_f32_16x16x32_bf16(afh[mt], bfl[nt], acc[mt][nt], 0, 0, 0);
                acc[mt][nt] = __builtin_amdgcn_mfma_f32_16x16x32_bf16(afh[mt], bfh[nt], acc[mt][nt], 0, 0, 0);
            }
    }

    // ---- epilogue 2: bias + relu + store + BN stats ----
    float* slot = bnslot + (size_t)(blockIdx.x & (BN_SLOTS - 1)) * 512;
#pragma unroll
    for (int nt = 0; nt < 4; ++nt) {
        int col = cb + nt * 16 + lr;
        float bv = bias2[col];
        float s = 0.f, qq = 0.f;
#pragma unroll
        for (int mt = 0; mt < 2; ++mt)
#pragma unroll
            for (int i = 0; i < 4; ++i) {
                int row = row0 + mt * 16 + lq * 4 + i;
                if (row < N_NODES) {
                    float o = fmaxf(acc[mt][nt][i] + bv, 0.f);
                    C[(size_t)row * 256 + col] = o;
                    s += o; qq += o * o;
                }
            }
        s += __shfl_xor(s, 16); s += __shfl_xor(s, 32);
        qq += __shfl_xor(qq, 16); qq += __shfl_xor(qq, 32);
        if (lq == 0) {
            atomicAdd(&slot[col], s);
            atomicAdd(&slot[256 + col], qq);
        }
    }
}

// reduce BN_SLOTS slots -> scale/shift
__global__ void bn_finalize_kernel(const float* __restrict__ slots,
                                   const float* __restrict__ g, const float* __restrict__ beta,
                                   float* __restrict__ scale, float* __restrict__ shift) {
    int c = threadIdx.x;
    float s = 0.f, q = 0.f;
    for (int k = 0; k < BN_SLOTS; ++k) {
        s += slots[(size_t)k * 512 + c];
        q += slots[(size_t)k * 512 + 256 + c];
    }
    float mu = s * (1.0f / N_NODES);
    float var = q * (1.0f / N_NODES) - mu * mu;
    float rstd = rsqrtf(var + 1e-5f);
    float sc = g[c] * rstd;
    scale[c] = sc;
    shift[c] = beta[c] - mu * sc;
}

// segmented sqrt-pool with BN applied at load; no atomics
__global__ __launch_bounds__(256)
void pool_seg_kernel(const float* __restrict__ h, const int* __restrict__ ptr,
                     const float* __restrict__ bnsc, const float* __restrict__ bnsh,
                     float* __restrict__ out, int nseg) {
    int t = threadIdx.x;
    int g = t >> 6;
    int j = t & 63;
    int s = blockIdx.x * 4 + g;
    if (s >= nseg) return;
    int beg = ptr[s], end = ptr[s + 1];
    int col = j << 2;
    float4 sc = *(const float4*)(bnsc + col);
    float4 sh = *(const float4*)(bnsh + col);
    float4 acc = {0.f, 0.f, 0.f, 0.f};
    for (int i = beg; i < end; ++i) {
        float4 v = *(const float4*)(h + (size_t)i * 256 + col);
        acc.x += fmaf(v.x, sc.x, sh.x);
        acc.y += fmaf(v.y, sc.y, sh.y);
        acc.z += fmaf(v.z, sc.z, sh.z);
        acc.w += fmaf(v.w, sc.w, sh.w);
    }
    float w = rsqrtf(fmaxf((float)(end - beg), 1.0f));
    float4 o = {acc.x * w, acc.y * w, acc.z * w, acc.w * w};
    *(float4*)(out + (size_t)s * 256 + col) = o;
}

// ---------------------------------------------------------------------------
extern "C" void kernel_launch(void* const* d_in, const int* in_sizes, int n_in,
                              void* d_out, int out_size, void* d_ws, size_t ws_size,
                              hipStream_t stream) {
    const float* x  = (const float*)d_in[0];
    const float* ea = (const float*)d_in[1];
    const int*   ei = (const int*)d_in[2];
    const int*   fb = (const int*)d_in[3];
    const int*   gb = (const int*)d_in[4];
    const float* W1[3]   = {(const float*)d_in[5],  (const float*)d_in[11], (const float*)d_in[17]};
    const float* B1[3]   = {(const float*)d_in[6],  (const float*)d_in[12], (const float*)d_in[18]};
    const float* W2[3]   = {(const float*)d_in[7],  (const float*)d_in[13], (const float*)d_in[19]};
    const float* B2[3]   = {(const float*)d_in[8],  (const float*)d_in[14], (const float*)d_in[20]};
    const float* G[3]    = {(const float*)d_in[9],  (const float*)d_in[15], (const float*)d_in[21]};
    const float* BETA[3] = {(const float*)d_in[10], (const float*)d_in[16], (const float*)d_in[22]};

    const int FIN[3] = {160, 288, 288};
    const int NBLK = (N_NODES + 255) / 256;      // scan blocks

    float* ws = (float*)d_ws;
    size_t off = 0;
    float* agg   = ws + off; off += (size_t)N_NODES * 288;
    float* xbuf  = ws + off; off += (size_t)N_NODES * 256;
    float* agg_e = ws + off; off += (size_t)N_NODES * DE;
    float* bnss  = ws + off; off += 3 * 512;                 // per layer: scale(256)|shift(256)
    float* bnslots = ws + off; off += (size_t)3 * BN_SLOTS * 512;
    unsigned short* w1hi[3]; unsigned short* w1lo[3];
    unsigned short* w2hi[3]; unsigned short* w2lo[3];
    {
        unsigned short* sw = (unsigned short*)(ws + off);
        unsigned short* sw0 = sw;
        for (int l = 0; l < 3; ++l) {
            w1hi[l] = sw; sw += 256 * FIN[l];
            w1lo[l] = sw; sw += 256 * FIN[l];
        }
        for (int l = 0; l < 3; ++l) {
            w2hi[l] = sw; sw += 256 * 256;
            w2lo[l] = sw; sw += 256 * 256;
        }
        off += (size_t)(sw - sw0 + 1) / 2;
    }
    int* iw      = (int*)(ws + off);
    int* row_ptr = iw;                     iw += N_NODES + 1;
    int* deg     = iw;                     iw += N_NODES;
    int* fill    = iw;                     iw += N_NODES;
    int* csr_src = iw;                     iw += N_EDGES;
    int* csr_eid = iw;                     iw += N_EDGES;
    int* frag_ptr = iw;                    iw += N_FRAG + 1;
    int* graph_ptr = iw;                   iw += N_GRAPH + 1;
    int* bsum    = iw;                     iw += NBLK;

    hipMemsetAsync(deg, 0, 2 * N_NODES * sizeof(int), stream);
    hipMemsetAsync(bnslots, 0, (size_t)3 * BN_SLOTS * 512 * sizeof(float), stream);

    // weight fragment-swizzle + bf16 hi/lo split (once per layer)
    for (int l = 0; l < 3; ++l) {
        bs_kernel<<<(FIN[l] * 256 + 255) / 256, 256, 0, stream>>>(W1[l], w1hi[l], w1lo[l], FIN[l]);
        bs_kernel<<<(256 * 256 + 255) / 256, 256, 0, stream>>>(W2[l], w2hi[l], w2lo[l], 256);
    }

    // CSR build (hierarchical scan)
    count_deg_kernel<<<(N_EDGES + 255) / 256, 256, 0, stream>>>(ei, deg);
    block_sum_kernel<<<NBLK, 256, 0, stream>>>(deg, bsum);
    top_scan_kernel<<<1, 256, 0, stream>>>(bsum, NBLK);
    final_scan_kernel<<<NBLK, 256, 0, stream>>>(deg, bsum, row_ptr);
    fill_csr_kernel<<<(N_EDGES + 255) / 256, 256, 0, stream>>>(ei, row_ptr, fill, csr_src, csr_eid);

    segptr_kernel<<<(N_FRAG + 1 + 255) / 256, 256, 0, stream>>>(fb, N_FRAG, frag_ptr);
    segptr_kernel<<<(N_GRAPH + 1 + 255) / 256, 256, 0, stream>>>(gb, N_GRAPH, graph_ptr);

    edge_gather_kernel<<<(N_NODES + 31) / 32, 256, 0, stream>>>(ea, row_ptr, csr_eid, agg_e);

    const int nblk_mlp = (N_NODES + 31) / 32;    // 1563 blocks, 32 rows each
    const float* xin = x;
    for (int l = 0; l < 3; ++l) {
        const int din = (l == 0) ? 128 : 256;
        const int fin = FIN[l];
        const int gl2 = (din == 128) ? 5 : 6;
        const int npb = 256 >> gl2;
        float* slotsL = bnslots + (size_t)l * BN_SLOTS * 512;
        float* bscale = bnss + l * 512;
        float* bshift = bscale + 256;
        const float* psc = (l > 0) ? bnss + (l - 1) * 512 : nullptr;  // prev layer BN
        const float* psh = (l > 0) ? psc + 256 : nullptr;

        if (l == 0)
            gather_agg_kernel<false><<<(N_NODES + npb - 1) / npb, 256, 0, stream>>>(
                xin, row_ptr, csr_src, agg_e, agg, nullptr, nullptr, din, fin, gl2);
        else
            gather_agg_kernel<true><<<(N_NODES + npb - 1) / npb, 256, 0, stream>>>(
                xin, row_ptr, csr_src, agg_e, agg, psc, psh, din, fin, gl2);
        fused_mlp_kernel<<<nblk_mlp, 256, 0, stream>>>(
            agg, w1hi[l], w1lo[l], B1[l], w2hi[l], w2lo[l], B2[l], xbuf, fin, slotsL);
        bn_finalize_kernel<<<1, 256, 0, stream>>>(slotsL, G[l], BETA[l], bscale, bshift);
        xin = xbuf;   // pre-BN h; BN applied by next consumer
    }

    const float* fsc = bnss + 2 * 512;   // layer-2 BN scale/shift
    const float* fsh = fsc + 256;
    pool_seg_kernel<<<(N_FRAG + 3) / 4, 256, 0, stream>>>(xbuf, frag_ptr, fsc, fsh,
                                                          (float*)d_out, N_FRAG);
    pool_seg_kernel<<<(N_GRAPH + 3) / 4, 256, 0, stream>>>(xbuf, graph_ptr, fsc, fsh,
                                                           (float*)d_out + (size_t)N_FRAG * 256, N_GRAPH);
}